// Round 1
// baseline (3058.982 us; speedup 1.0000x reference)
//
#include <hip/hip_runtime.h>
#include <stdint.h>

// Problem constants
#define N_PTS 65536
#define W_WIN 2048   // N/32
#define LCAT  216    // 3*40 (xyz) + 3*32 (rgb) concatenated table width

// ---- bf16 helpers (RNE) ----
__device__ __forceinline__ uint16_t f2b(float x) {
    uint32_t u = __float_as_uint(x);
    u += 0x7FFFu + ((u >> 16) & 1u);
    return (uint16_t)(u >> 16);
}
__device__ __forceinline__ float b2f(uint32_t b) {
    return __uint_as_float(b << 16);
}

// ============================================================================
// Kernel 1: qkv = feats[perm[s]] @ qkv_w^T + b   (store bf16, q-part scaled)
// BM=128 BN=64 BK=32, 256 threads, 8x4 micro-tile
// ============================================================================
__global__ __launch_bounds__(256) void qkv_gemm(
    const float* __restrict__ feats, const int* __restrict__ perm,
    const float* __restrict__ Wq, const float* __restrict__ bq,
    uint16_t* __restrict__ qkv_out)
{
    __shared__ float As[32][132];   // [k][m], padded
    __shared__ float Bs[32][68];    // [k][n], padded
    __shared__ int   ps[128];
    const int t  = threadIdx.x;
    const int s0 = blockIdx.x * 128;
    const int n0 = blockIdx.y * 64;
    if (t < 128) ps[t] = perm[s0 + t];
    __syncthreads();
    const int ty = t >> 4, tx = t & 15;
    float acc[8][4] = {};
    for (int k0 = 0; k0 < 256; k0 += 32) {
        #pragma unroll
        for (int r = 0; r < 4; r++) {
            int idx = t + r * 256;
            int m = idx >> 3, k4 = idx & 7;
            float4 v = *(const float4*)(feats + (size_t)ps[m] * 256 + k0 + k4 * 4);
            As[k4*4+0][m] = v.x; As[k4*4+1][m] = v.y; As[k4*4+2][m] = v.z; As[k4*4+3][m] = v.w;
        }
        #pragma unroll
        for (int r = 0; r < 2; r++) {
            int idx = t + r * 256;
            int n = idx >> 3, k4 = idx & 7;
            float4 v = *(const float4*)(Wq + (size_t)(n0 + n) * 256 + k0 + k4 * 4);
            Bs[k4*4+0][n] = v.x; Bs[k4*4+1][n] = v.y; Bs[k4*4+2][n] = v.z; Bs[k4*4+3][n] = v.w;
        }
        __syncthreads();
        #pragma unroll
        for (int kk = 0; kk < 32; kk++) {
            float a[8], b[4];
            *(float4*)&a[0] = *(const float4*)&As[kk][ty*8];
            *(float4*)&a[4] = *(const float4*)&As[kk][ty*8+4];
            *(float4*)&b[0] = *(const float4*)&Bs[kk][tx*4];
            #pragma unroll
            for (int i = 0; i < 8; i++)
                #pragma unroll
                for (int j = 0; j < 4; j++)
                    acc[i][j] += a[i] * b[j];
        }
        __syncthreads();
    }
    #pragma unroll
    for (int i = 0; i < 8; i++) {
        int s = s0 + ty*8 + i;
        uint16_t* orow = qkv_out + (size_t)s * 768 + n0 + tx*4;
        float v[4];
        #pragma unroll
        for (int j = 0; j < 4; j++) {
            int n = n0 + tx*4 + j;
            v[j] = acc[i][j] + bq[n];
            if (n < 256) v[j] *= 0.25f;   // q * hd^-0.5 (after bias, as in reference)
        }
        uint32_t p0 = (uint32_t)f2b(v[0]) | ((uint32_t)f2b(v[1]) << 16);
        uint32_t p1 = (uint32_t)f2b(v[2]) | ((uint32_t)f2b(v[3]) << 16);
        *(uint2*)(void*)orow = make_uint2(p0, p1);
    }
}

// ============================================================================
// Kernel 2: per-window attention with relative positional tables.
// One block per window (2048 blocks, 256 threads), loop over 16 heads.
// Concat table index lc in [0,216): [xyz d0|d1|d2 (40 each) | rgb d0|d1|d2 (32 each)]
// ============================================================================
__global__ __launch_bounds__(256) void win_attn(
    const uint16_t* __restrict__ qkv,      // [N][768] bf16, s-order, q pre-scaled
    const int* __restrict__ perm,
    const float* __restrict__ ncoords,     // [N][6]
    const float* __restrict__ qtx, const float* __restrict__ ktx, const float* __restrict__ vtx,
    const float* __restrict__ qtr, const float* __restrict__ ktr, const float* __restrict__ vtr,
    uint16_t* __restrict__ attn_o)         // [N][256] bf16, s-order
{
    __shared__ float bufA[6912];           // Pqk[i][216]  ->  St[216][32]
    __shared__ float bufB[6912];           // Pkq[j][216]  ->  vst[216][16] + red[4][512]@4096
    __shared__ float att[32*36];           // att[j][i], stride 36 (align+bank pad)
    __shared__ float qs[512], ks[512], vs[512];
    __shared__ float cs[192];              // scaled coords [i][6]
    __shared__ unsigned char lcix[32*32*6];// concat indices per (i,j)

    const int t  = threadIdx.x;
    const int w  = blockIdx.x;
    const int s0 = w * 32;

    // ---- phase 0: coords + relative indices (once per window) ----
    if (t < 192) {
        int i = t / 6, d = t % 6;
        int p = perm[s0 + i];
        cs[t] = ncoords[(size_t)p * 6 + d] * (d < 3 ? 4.0f : 8.0f);  // *QS / *CQS
    }
    __syncthreads();
    #pragma unroll
    for (int r = 0; r < 4; r++) {
        int pr = (t << 2) + r;             // (i,j) pair id
        int i = pr >> 5, j = pr & 31;
        unsigned char* o = &lcix[pr * 6];
        #pragma unroll
        for (int m = 0; m < 3; m++) {
            int ix = (int)floorf(cs[i*6+m] - cs[j*6+m]) + 20;
            ix = ix < 0 ? 0 : (ix > 39 ? 39 : ix);
            o[m] = (unsigned char)(ix + m*40);
        }
        #pragma unroll
        for (int m = 0; m < 3; m++) {
            int ix = (int)floorf(cs[i*6+3+m] - cs[j*6+3+m]) + 16;
            ix = ix < 0 ? 0 : (ix > 31 ? 31 : ix);
            o[3+m] = (unsigned char)(ix + 120 + m*32);
        }
    }
    // visibility of lcix covered by the first in-loop barrier

    for (int h = 0; h < 16; h++) {
        // ---- load q/k/v head tiles (bf16 -> f32 LDS) ----
        for (int r = t; r < 1536; r += 256) {
            int part = r >> 9;             // 0=q 1=k 2=v
            int e = r & 511;
            int i = e >> 4, c = e & 15;
            float f = b2f((uint32_t)qkv[(size_t)(s0+i)*768 + part*256 + h*16 + c]);
            float* dst = (part == 0) ? qs : (part == 1) ? ks : vs;
            dst[e] = f;
        }
        __syncthreads();

        // ---- P tables: Pqk[i][lc] = q[i]·ktab[lc], Pkq[j][lc] = k[j]·qtab[lc] ----
        {
            int side  = t >> 7;            // 0: Pqk (key tables), 1: Pkq (query tables)
            int pi    = t & 31;
            int chunk = (t >> 5) & 3;      // 4 chunks of 54 lc
            const float* rowq = (side == 0) ? &qs[pi*16] : &ks[pi*16];
            float qr[16];
            #pragma unroll
            for (int c = 0; c < 4; c++) {
                float4 v = *(const float4*)&rowq[c*4];
                qr[c*4+0]=v.x; qr[c*4+1]=v.y; qr[c*4+2]=v.z; qr[c*4+3]=v.w;
            }
            const float* txyz = (side == 0) ? ktx : qtx;
            const float* trgb = (side == 0) ? ktr : qtr;
            float* Pout = (side == 0) ? bufA : bufB;
            for (int it = 0; it < 54; it++) {
                int lc = chunk*54 + it;
                const float* trow = (lc < 120)
                    ? (txyz + ((size_t)lc*16 + h)*16)            // d*40+l == lc
                    : (trgb + ((size_t)(lc-120)*16 + h)*16);     // d*32+l == lc-120
                float a = 0.f;
                #pragma unroll
                for (int c = 0; c < 4; c++) {
                    float4 v = *(const float4*)&trow[c*4];
                    a += qr[c*4+0]*v.x + qr[c*4+1]*v.y + qr[c*4+2]*v.z + qr[c*4+3]*v.w;
                }
                Pout[pi*216 + lc] = a;
            }
        }
        __syncthreads();

        // ---- logits: att[j][i] = q[i]·k[j] + sum_m Pqk[i][lc] + Pkq[j][lc] ----
        {
            int ii = t >> 3, jsub = t & 7;
            float qr[16];
            #pragma unroll
            for (int c = 0; c < 4; c++) {
                float4 v = *(const float4*)&qs[ii*16 + c*4];
                qr[c*4+0]=v.x; qr[c*4+1]=v.y; qr[c*4+2]=v.z; qr[c*4+3]=v.w;
            }
            #pragma unroll
            for (int jj = 0; jj < 4; jj++) {
                int j = jsub + jj*8;
                float a = 0.f;
                #pragma unroll
                for (int c = 0; c < 4; c++) {
                    float4 v = *(const float4*)&ks[j*16 + c*4];
                    a += qr[c*4+0]*v.x + qr[c*4+1]*v.y + qr[c*4+2]*v.z + qr[c*4+3]*v.w;
                }
                const unsigned char* o = &lcix[(ii*32 + j)*6];
                #pragma unroll
                for (int m = 0; m < 6; m++) {
                    int lc = o[m];
                    a += bufA[ii*216 + lc] + bufB[j*216 + lc];
                }
                att[j*36 + ii] = a;
            }
        }
        __syncthreads();

        // ---- softmax over j (8 threads per row) + zero St + stage value tables ----
        {
            int i = t >> 3, sub = t & 7;
            float v[4]; float mx = -3.0e38f;
            #pragma unroll
            for (int r = 0; r < 4; r++) { v[r] = att[(sub + r*8)*36 + i]; mx = fmaxf(mx, v[r]); }
            #pragma unroll
            for (int d2 = 1; d2 < 8; d2 <<= 1) mx = fmaxf(mx, __shfl_xor(mx, d2, 64));
            float sm = 0.f;
            #pragma unroll
            for (int r = 0; r < 4; r++) { v[r] = __expf(v[r] - mx); sm += v[r]; }
            #pragma unroll
            for (int d2 = 1; d2 < 8; d2 <<= 1) sm += __shfl_xor(sm, d2, 64);
            float inv = 1.0f / sm;
            #pragma unroll
            for (int r = 0; r < 4; r++) att[(sub + r*8)*36 + i] = v[r] * inv;
        }
        for (int r = t; r < 6912; r += 256) bufA[r] = 0.f;        // St[216][32] = 0
        for (int r = t; r < 3456; r += 256) {                    // vst[216][16]
            int lc = r >> 4, c = r & 15;
            const float* trow = (lc < 120)
                ? (vtx + ((size_t)lc*16 + h)*16)
                : (vtr + ((size_t)(lc-120)*16 + h)*16);
            bufB[r] = trow[c];
        }
        __syncthreads();

        // ---- scatter: St[lc][i] += a[i][j]  (6 segments disjoint -> no races per column) ----
        if (t < 192) {
            int i = t & 31, m = t >> 5;
            const unsigned char* o = &lcix[i*32*6 + m];
            #pragma unroll 8
            for (int j = 0; j < 32; j++) {
                int lc = o[j*6];
                atomicAdd(&bufA[lc*32 + i], att[j*36 + i]);
            }
        }
        __syncthreads();

        // ---- PV: out[i][c] = sum_lc St[lc][i]*vst[lc][c] + sum_j a[i][j]*v[j][c] ----
        {
            int wv = t >> 6;               // wave id: K-chunk
            int lane = t & 63;
            int i0 = (lane >> 3) * 4;      // 8 i-blocks of 4
            int c0 = (lane & 7) * 2;       // 8 c-blocks of 2
            float a00=0,a01=0,a10=0,a11=0,a20=0,a21=0,a30=0,a31=0;
            for (int it = 0; it < 54; it++) {
                int lc = wv*54 + it;
                float4 sv = *(const float4*)&bufA[lc*32 + i0];
                float2 vv = *(const float2*)&bufB[lc*16 + c0];
                a00 += sv.x*vv.x; a01 += sv.x*vv.y;
                a10 += sv.y*vv.x; a11 += sv.y*vv.y;
                a20 += sv.z*vv.x; a21 += sv.z*vv.y;
                a30 += sv.w*vv.x; a31 += sv.w*vv.y;
            }
            #pragma unroll
            for (int jt = 0; jt < 8; jt++) {
                int j = wv*8 + jt;
                float4 av = *(const float4*)&att[j*36 + i0];
                float2 vv = *(const float2*)&vs[j*16 + c0];
                a00 += av.x*vv.x; a01 += av.x*vv.y;
                a10 += av.y*vv.x; a11 += av.y*vv.y;
                a20 += av.z*vv.x; a21 += av.z*vv.y;
                a30 += av.w*vv.x; a31 += av.w*vv.y;
            }
            float* red = bufB + 4096 + wv*512;
            *(float2*)&red[(i0+0)*16 + c0] = make_float2(a00,a01);
            *(float2*)&red[(i0+1)*16 + c0] = make_float2(a10,a11);
            *(float2*)&red[(i0+2)*16 + c0] = make_float2(a20,a21);
            *(float2*)&red[(i0+3)*16 + c0] = make_float2(a30,a31);
        }
        __syncthreads();

        // ---- reduce 4 wave-partials + store (bf16) ----
        {
            int o2 = t * 2;
            float2 r0 = *(const float2*)&bufB[4096 + o2];
            float2 r1 = *(const float2*)&bufB[4096 + 512 + o2];
            float2 r2 = *(const float2*)&bufB[4096 + 1024 + o2];
            float2 r3 = *(const float2*)&bufB[4096 + 1536 + o2];
            float sx = r0.x + r1.x + r2.x + r3.x;
            float sy = r0.y + r1.y + r2.y + r3.y;
            int i = o2 >> 4, c = o2 & 15;
            uint32_t pk = (uint32_t)f2b(sx) | ((uint32_t)f2b(sy) << 16);
            *(uint32_t*)(void*)(attn_o + (size_t)(s0+i)*256 + h*16 + c) = pk;
        }
        __syncthreads();
    }
}

// ============================================================================
// Kernel 3: out[perm[s]] = attn_out[s] @ proj_w^T + proj_b  (bf16 A, f32 out)
// ============================================================================
__global__ __launch_bounds__(256) void proj_gemm(
    const uint16_t* __restrict__ Abf, const int* __restrict__ perm,
    const float* __restrict__ Wp, const float* __restrict__ bp,
    float* __restrict__ out)
{
    __shared__ float As[32][132];
    __shared__ float Bs[32][68];
    __shared__ int   ps[128];
    const int t  = threadIdx.x;
    const int s0 = blockIdx.x * 128;
    const int n0 = blockIdx.y * 64;
    if (t < 128) ps[t] = perm[s0 + t];
    __syncthreads();
    const int ty = t >> 4, tx = t & 15;
    float acc[8][4] = {};
    for (int k0 = 0; k0 < 256; k0 += 32) {
        #pragma unroll
        for (int r = 0; r < 4; r++) {
            int idx = t + r * 256;
            int m = idx >> 3, k4 = idx & 7;
            uint2 raw = *(const uint2*)(const void*)(Abf + (size_t)(s0+m) * 256 + k0 + k4 * 4);
            As[k4*4+0][m] = b2f(raw.x & 0xffffu);
            As[k4*4+1][m] = b2f(raw.x >> 16);
            As[k4*4+2][m] = b2f(raw.y & 0xffffu);
            As[k4*4+3][m] = b2f(raw.y >> 16);
        }
        #pragma unroll
        for (int r = 0; r < 2; r++) {
            int idx = t + r * 256;
            int n = idx >> 3, k4 = idx & 7;
            float4 v = *(const float4*)(Wp + (size_t)(n0 + n) * 256 + k0 + k4 * 4);
            Bs[k4*4+0][n] = v.x; Bs[k4*4+1][n] = v.y; Bs[k4*4+2][n] = v.z; Bs[k4*4+3][n] = v.w;
        }
        __syncthreads();
        #pragma unroll
        for (int kk = 0; kk < 32; kk++) {
            float a[8], b[4];
            *(float4*)&a[0] = *(const float4*)&As[kk][ty*8];
            *(float4*)&a[4] = *(const float4*)&As[kk][ty*8+4];
            *(float4*)&b[0] = *(const float4*)&Bs[kk][tx*4];
            #pragma unroll
            for (int i = 0; i < 8; i++)
                #pragma unroll
                for (int j = 0; j < 4; j++)
                    acc[i][j] += a[i] * b[j];
        }
        __syncthreads();
    }
    #pragma unroll
    for (int i = 0; i < 8; i++) {
        int prow = ps[ty*8 + i];
        float4 v;
        v.x = acc[i][0] + bp[n0+tx*4+0];
        v.y = acc[i][1] + bp[n0+tx*4+1];
        v.z = acc[i][2] + bp[n0+tx*4+2];
        v.w = acc[i][3] + bp[n0+tx*4+3];
        *(float4*)(out + (size_t)prow*256 + n0 + tx*4) = v;
    }
}

// ============================================================================
extern "C" void kernel_launch(void* const* d_in, const int* in_sizes, int n_in,
                              void* d_out, int out_size, void* d_ws, size_t ws_size,
                              hipStream_t stream) {
    const float* feats   = (const float*)d_in[0];
    const float* ncoords = (const float*)d_in[1];
    const int*   perm    = (const int*)d_in[2];
    const float* qtx     = (const float*)d_in[3];
    const float* ktx     = (const float*)d_in[4];
    const float* vtx     = (const float*)d_in[5];
    const float* qtr     = (const float*)d_in[6];
    const float* ktr     = (const float*)d_in[7];
    const float* vtr     = (const float*)d_in[8];
    const float* qkv_w   = (const float*)d_in[9];
    const float* qkv_b   = (const float*)d_in[10];
    const float* proj_w  = (const float*)d_in[11];
    const float* proj_b  = (const float*)d_in[12];

    uint16_t* qkv_s  = (uint16_t*)d_ws;                                  // N*768 bf16 (100.7 MB)
    uint16_t* attn_o = (uint16_t*)((char*)d_ws + (size_t)N_PTS*768*2);   // N*256 bf16 (33.6 MB)

    dim3 g1(512, 12);
    qkv_gemm<<<g1, 256, 0, stream>>>(feats, perm, qkv_w, qkv_b, qkv_s);

    win_attn<<<W_WIN, 256, 0, stream>>>(qkv_s, perm, ncoords,
                                        qtx, ktx, vtx, qtr, ktr, vtr, attn_o);

    dim3 g3(512, 4);
    proj_gemm<<<g3, 256, 0, stream>>>(attn_o, perm, proj_w, proj_b, (float*)d_out);
}

// Round 3
// 2467.718 us; speedup vs baseline: 1.2396x; 1.2396x over previous
//
#include <hip/hip_runtime.h>
#include <stdint.h>

#define N_PTS 65536
#define W_WIN 2048

using short8 = __attribute__((ext_vector_type(8))) short;
using f32x4  = __attribute__((ext_vector_type(4))) float;

// ---- bf16 helpers (RNE) ----
__device__ __forceinline__ uint16_t f2b(float x) {
    uint32_t u = __float_as_uint(x);
    u += 0x7FFFu + ((u >> 16) & 1u);
    return (uint16_t)(u >> 16);
}
__device__ __forceinline__ float b2f(uint32_t b) {
    return __uint_as_float(b << 16);
}
__device__ __forceinline__ short8 pack8(float4 a, float4 b) {
    short8 r;
    r[0]=(short)f2b(a.x); r[1]=(short)f2b(a.y); r[2]=(short)f2b(a.z); r[3]=(short)f2b(a.w);
    r[4]=(short)f2b(b.x); r[5]=(short)f2b(b.y); r[6]=(short)f2b(b.z); r[7]=(short)f2b(b.w);
    return r;
}

// ============================================================================
// Kernel 1: qkv = feats[perm[s]] @ qkv_w^T + b   (store bf16, q-part scaled)
// ============================================================================
__global__ __launch_bounds__(256) void qkv_gemm(
    const float* __restrict__ feats, const int* __restrict__ perm,
    const float* __restrict__ Wq, const float* __restrict__ bq,
    uint16_t* __restrict__ qkv_out)
{
    __shared__ float As[32][132];
    __shared__ float Bs[32][68];
    __shared__ int   ps[128];
    const int t  = threadIdx.x;
    const int s0 = blockIdx.x * 128;
    const int n0 = blockIdx.y * 64;
    if (t < 128) ps[t] = perm[s0 + t];
    __syncthreads();
    const int ty = t >> 4, tx = t & 15;
    float acc[8][4] = {};
    for (int k0 = 0; k0 < 256; k0 += 32) {
        #pragma unroll
        for (int r = 0; r < 4; r++) {
            int idx = t + r * 256;
            int m = idx >> 3, k4 = idx & 7;
            float4 v = *(const float4*)(feats + (size_t)ps[m] * 256 + k0 + k4 * 4);
            As[k4*4+0][m] = v.x; As[k4*4+1][m] = v.y; As[k4*4+2][m] = v.z; As[k4*4+3][m] = v.w;
        }
        #pragma unroll
        for (int r = 0; r < 2; r++) {
            int idx = t + r * 256;
            int n = idx >> 3, k4 = idx & 7;
            float4 v = *(const float4*)(Wq + (size_t)(n0 + n) * 256 + k0 + k4 * 4);
            Bs[k4*4+0][n] = v.x; Bs[k4*4+1][n] = v.y; Bs[k4*4+2][n] = v.z; Bs[k4*4+3][n] = v.w;
        }
        __syncthreads();
        #pragma unroll
        for (int kk = 0; kk < 32; kk++) {
            float a[8], b[4];
            *(float4*)&a[0] = *(const float4*)&As[kk][ty*8];
            *(float4*)&a[4] = *(const float4*)&As[kk][ty*8+4];
            *(float4*)&b[0] = *(const float4*)&Bs[kk][tx*4];
            #pragma unroll
            for (int i = 0; i < 8; i++)
                #pragma unroll
                for (int j = 0; j < 4; j++)
                    acc[i][j] += a[i] * b[j];
        }
        __syncthreads();
    }
    #pragma unroll
    for (int i = 0; i < 8; i++) {
        int s = s0 + ty*8 + i;
        uint16_t* orow = qkv_out + (size_t)s * 768 + n0 + tx*4;
        float v[4];
        #pragma unroll
        for (int j = 0; j < 4; j++) {
            int n = n0 + tx*4 + j;
            v[j] = acc[i][j] + bq[n];
            if (n < 256) v[j] *= 0.25f;
        }
        uint32_t p0 = (uint32_t)f2b(v[0]) | ((uint32_t)f2b(v[1]) << 16);
        uint32_t p1 = (uint32_t)f2b(v[2]) | ((uint32_t)f2b(v[3]) << 16);
        *(uint2*)(void*)orow = make_uint2(p0, p1);
    }
}

// ============================================================================
// Kernel 2: per-window attention, MFMA-based (16x16x32 bf16, K=16 zero-padded)
// Block = 256 thr (4 waves) per window; heads sequential; 5 barriers/head.
// lc concat: [xyz d0|d1|d2 (40 each) | 120 + rgb d0|d1|d2 (32 each)] = 216
// Pqk_ext cols: 0..215 table, 216..247 = QK^T (j), 248..255 pad.
// ============================================================================
__global__ __launch_bounds__(256, 3) void win_attn2(
    const uint16_t* __restrict__ qkv,      // [N][768] bf16, q pre-scaled
    const int* __restrict__ perm,
    const float* __restrict__ ncoords,
    const float* __restrict__ qtx, const float* __restrict__ ktx, const float* __restrict__ vtx,
    const float* __restrict__ qtr, const float* __restrict__ ktr, const float* __restrict__ vtr,
    uint16_t* __restrict__ attn_o)         // [N][256] bf16
{
    __shared__ __align__(16) unsigned char smem[54144];
    uint16_t* Pqk  = (uint16_t*)(smem + 0);        // [32][264] bf16 (16896 B)
    uint16_t* Pkq  = (uint16_t*)(smem + 16896);    // [32][232] bf16 (14848 B)
    float*    Sf   = (float*)(smem + 0);           // [32][228] f32 (29184 B) aliases P
    float*    att  = (float*)(smem + 31744);       // [32][36] f32 (4608 B)
    uint16_t* vwT  = (uint16_t*)(smem + 36352);    // [16][40] bf16 (1280 B)
    uint8_t*  lcix = (uint8_t*)(smem + 37632);     // [1024][6] (6144 B)
    uint16_t* vtT  = (uint16_t*)(smem + 43776);    // [16][232] bf16 (7424 B)
    float*    oacc = (float*)(smem + 51200);       // [32][17] f32 (2176 B)
    float*    cs   = (float*)(smem + 53376);       // 192 f32 (768 B)

    const int t     = threadIdx.x;
    const int w     = blockIdx.x;
    const int sBase = w * 32;
    const int wv = t >> 6;
    const int ln = t & 63;
    const int g  = ln >> 4;      // k-group 0..3 (g>=2 -> zero pad half of K=32)
    const int lr = ln & 15;      // row/col within 16

    // ---- phase 0: coords + relative concat indices ----
    if (t < 192) {
        int i = t / 6, d = t % 6;
        int p = perm[sBase + i];
        cs[t] = ncoords[(size_t)p * 6 + d] * (d < 3 ? 4.0f : 8.0f);
    }
    __syncthreads();
    #pragma unroll
    for (int r = 0; r < 4; r++) {
        int pr = t * 4 + r;
        int i = pr >> 5, j = pr & 31;
        uint8_t* o = &lcix[pr * 6];
        #pragma unroll
        for (int m = 0; m < 3; m++) {
            int ix = (int)floorf(cs[i*6+m] - cs[j*6+m]) + 20;
            ix = ix < 0 ? 0 : (ix > 39 ? 39 : ix);
            o[m] = (uint8_t)(ix + m*40);
        }
        #pragma unroll
        for (int m = 0; m < 3; m++) {
            int ix = (int)floorf(cs[i*6+3+m] - cs[j*6+3+m]) + 16;
            ix = ix < 0 ? 0 : (ix > 31 ? 31 : ix);
            o[3+m] = (uint8_t)(ix + 120 + m*32);
        }
    }
    // lcix visibility covered by b1 below

    const int isPkq = wv >> 1;   // waves 0,1: Pqk_ext; waves 2,3: Pkq
    const int mt    = wv & 1;    // M-tile (rows mt*16..mt*16+15)

    for (int h = 0; h < 16; h++) {
        const int hc0 = h * 16;
        // ---------------- Phase P: MFMA P-tables + vwT/vtT staging ----------------
        {   // v^T (16c x 32j) into LDS
            int e = t * 2, c = e & 15, j = e >> 4;
            uint32_t pk = *(const uint32_t*)(const void*)(qkv + (size_t)(sBase + j) * 768 + 512 + hc0 + c);
            vwT[c * 40 + j]       = (uint16_t)(pk & 0xffffu);
            vwT[(c + 1) * 40 + j] = (uint16_t)(pk >> 16);
        }
        for (int e = t; e < 3584; e += 256) {   // vtab^T head slice (coalesced reads)
            int lc = e >> 4, c = e & 15;
            float val = 0.f;
            if (lc < 120)      val = vtx[(size_t)lc * 256 + hc0 + c];
            else if (lc < 216) val = vtr[(size_t)(lc - 120) * 256 + hc0 + c];
            vtT[c * 232 + lc] = f2b(val);
        }
        {
            short8 afrag = {0,0,0,0,0,0,0,0};
            if (g < 2)
                afrag = *(const short8*)(const void*)(qkv + (size_t)(sBase + mt*16 + lr) * 768 + isPkq*256 + hc0 + g*8);
            const int ntmax   = isPkq ? 14 : 16;
            const float* txyz = isPkq ? qtx : ktx;
            const float* trgb = isPkq ? qtr : ktr;
            uint16_t* Pout    = isPkq ? Pkq : Pqk;
            const int str     = isPkq ? 232 : 264;
            for (int nt = 0; nt < ntmax; nt++) {
                int col = nt * 16 + lr;
                short8 bfrag = {0,0,0,0,0,0,0,0};
                if (g < 2) {
                    if (col < 120) {
                        const float* p = txyz + (size_t)col * 256 + hc0 + g*8;
                        bfrag = pack8(*(const float4*)p, *(const float4*)(p + 4));
                    } else if (col < 216) {
                        const float* p = trgb + (size_t)(col - 120) * 256 + hc0 + g*8;
                        bfrag = pack8(*(const float4*)p, *(const float4*)(p + 4));
                    } else if (!isPkq && col < 248) {
                        bfrag = *(const short8*)(const void*)(qkv + (size_t)(sBase + col - 216) * 768 + 256 + hc0 + g*8);
                    }
                }
                f32x4 d = {0.f,0.f,0.f,0.f};
                d = __builtin_amdgcn_mfma_f32_16x16x32_bf16(afrag, bfrag, d, 0, 0, 0);
                #pragma unroll
                for (int r = 0; r < 4; r++)
                    Pout[(size_t)(mt*16 + g*4 + r) * str + col] = f2b(d[r]);
            }
        }
        __syncthreads();   // b1: P/vwT/vtT -> G

        // ---------------- Phase G: gather logits ----------------
        {
            int i = t >> 3, jsub = t & 7;
            #pragma unroll
            for (int jj = 0; jj < 4; jj++) {
                int j = jsub + jj * 8;
                float a = b2f(Pqk[i * 264 + 216 + j]);
                const uint8_t* o = &lcix[(i * 32 + j) * 6];
                #pragma unroll
                for (int m = 0; m < 6; m++) {
                    int lc = o[m];
                    a += b2f(Pqk[i * 264 + lc]) + b2f(Pkq[j * 232 + lc]);
                }
                att[i * 36 + j] = a;
            }
        }
        __syncthreads();   // b2: att -> SM

        // ---------------- Phase SM: softmax + zero S/oacc ----------------
        {
            int i = t >> 3, sub = t & 7;
            float v[4]; float mx = -3.0e38f;
            #pragma unroll
            for (int r = 0; r < 4; r++) { v[r] = att[i*36 + sub + r*8]; mx = fmaxf(mx, v[r]); }
            #pragma unroll
            for (int d2 = 1; d2 < 8; d2 <<= 1) mx = fmaxf(mx, __shfl_xor(mx, d2, 64));
            float sm = 0.f;
            #pragma unroll
            for (int r = 0; r < 4; r++) { v[r] = __expf(v[r] - mx); sm += v[r]; }
            #pragma unroll
            for (int d2 = 1; d2 < 8; d2 <<= 1) sm += __shfl_xor(sm, d2, 64);
            float inv = 1.0f / sm;
            #pragma unroll
            for (int r = 0; r < 4; r++) att[i*36 + sub + r*8] = v[r] * inv;
        }
        for (int r = t; r < 7296; r += 256) Sf[r] = 0.f;     // 32*228 (S aliases P, dead now)
        for (int r = t; r < 544; r += 256) oacc[r] = 0.f;    // 32*17
        __syncthreads();   // b3: S-zero/att -> SC

        // ---------------- Phase SC: scatter a into S[i][lc] ----------------
        if (t < 192) {
            int i = t & 31, m = t >> 5;
            const uint8_t* o = &lcix[i * 32 * 6 + m];
            float* Srow = &Sf[i * 228];
            #pragma unroll 4
            for (int j = 0; j < 32; j++)
                atomicAdd(&Srow[o[j * 6]], att[i * 36 + j]);
        }
        __syncthreads();   // b4: S -> PV

        // ---------------- Phase PV: [S|a](32x256) @ [vtab;vw](256x16), K-split ----------------
        {
            f32x4 acc0 = {0.f,0.f,0.f,0.f}, acc1 = {0.f,0.f,0.f,0.f};
            #pragma unroll
            for (int s2 = 0; s2 < 2; s2++) {
                int kt = wv * 2 + s2;
                short8 bfrag;
                if (kt < 7) bfrag = *(const short8*)(const void*)(vtT + lr * 232 + kt * 32 + g * 8);
                else        bfrag = *(const short8*)(const void*)(vwT + lr * 40 + g * 8);
                {   // mt = 0
                    short8 af;
                    if (kt < 7) {
                        const float* p = &Sf[(size_t)lr * 228 + kt*32 + g*8];
                        af = pack8(*(const float4*)p, *(const float4*)(p+4));
                    } else {
                        const float* p = &att[lr * 36 + g*8];
                        af = pack8(*(const float4*)p, *(const float4*)(p+4));
                    }
                    acc0 = __builtin_amdgcn_mfma_f32_16x16x32_bf16(af, bfrag, acc0, 0, 0, 0);
                }
                {   // mt = 1
                    short8 af;
                    if (kt < 7) {
                        const float* p = &Sf[(size_t)(16 + lr) * 228 + kt*32 + g*8];
                        af = pack8(*(const float4*)p, *(const float4*)(p+4));
                    } else {
                        const float* p = &att[(16 + lr) * 36 + g*8];
                        af = pack8(*(const float4*)p, *(const float4*)(p+4));
                    }
                    acc1 = __builtin_amdgcn_mfma_f32_16x16x32_bf16(af, bfrag, acc1, 0, 0, 0);
                }
            }
            #pragma unroll
            for (int r = 0; r < 4; r++) {
                atomicAdd(&oacc[(g*4 + r) * 17 + lr], acc0[r]);
                atomicAdd(&oacc[(16 + g*4 + r) * 17 + lr], acc1[r]);
            }
        }
        __syncthreads();   // b5: oacc -> R

        // ---------------- Phase R: store head output (bf16) ----------------
        {
            int o2 = t * 2;
            int i = o2 >> 4, c = o2 & 15;
            float x = oacc[i * 17 + c], y = oacc[i * 17 + c + 1];
            uint32_t pk = (uint32_t)f2b(x) | ((uint32_t)f2b(y) << 16);
            *(uint32_t*)(void*)(attn_o + (size_t)(sBase + i) * 256 + hc0 + c) = pk;
        }
        // no trailing barrier needed: next-head P writes (P-region/vwT/vtT) are
        // ordered after b5; oacc reread hazard is covered by next b1/b2.
    }
}

// ============================================================================
// Kernel 3: out[perm[s]] = attn_out[s] @ proj_w^T + proj_b
// ============================================================================
__global__ __launch_bounds__(256) void proj_gemm(
    const uint16_t* __restrict__ Abf, const int* __restrict__ perm,
    const float* __restrict__ Wp, const float* __restrict__ bp,
    float* __restrict__ out)
{
    __shared__ float As[32][132];
    __shared__ float Bs[32][68];
    __shared__ int   ps[128];
    const int t  = threadIdx.x;
    const int s0 = blockIdx.x * 128;
    const int n0 = blockIdx.y * 64;
    if (t < 128) ps[t] = perm[s0 + t];
    __syncthreads();
    const int ty = t >> 4, tx = t & 15;
    float acc[8][4] = {};
    for (int k0 = 0; k0 < 256; k0 += 32) {
        #pragma unroll
        for (int r = 0; r < 4; r++) {
            int idx = t + r * 256;
            int m = idx >> 3, k4 = idx & 7;
            uint2 raw = *(const uint2*)(const void*)(Abf + (size_t)(s0+m) * 256 + k0 + k4 * 4);
            As[k4*4+0][m] = b2f(raw.x & 0xffffu);
            As[k4*4+1][m] = b2f(raw.x >> 16);
            As[k4*4+2][m] = b2f(raw.y & 0xffffu);
            As[k4*4+3][m] = b2f(raw.y >> 16);
        }
        #pragma unroll
        for (int r = 0; r < 2; r++) {
            int idx = t + r * 256;
            int n = idx >> 3, k4 = idx & 7;
            float4 v = *(const float4*)(Wp + (size_t)(n0 + n) * 256 + k0 + k4 * 4);
            Bs[k4*4+0][n] = v.x; Bs[k4*4+1][n] = v.y; Bs[k4*4+2][n] = v.z; Bs[k4*4+3][n] = v.w;
        }
        __syncthreads();
        #pragma unroll
        for (int kk = 0; kk < 32; kk++) {
            float a[8], b[4];
            *(float4*)&a[0] = *(const float4*)&As[kk][ty*8];
            *(float4*)&a[4] = *(const float4*)&As[kk][ty*8+4];
            *(float4*)&b[0] = *(const float4*)&Bs[kk][tx*4];
            #pragma unroll
            for (int i = 0; i < 8; i++)
                #pragma unroll
                for (int j = 0; j < 4; j++)
                    acc[i][j] += a[i] * b[j];
        }
        __syncthreads();
    }
    #pragma unroll
    for (int i = 0; i < 8; i++) {
        int prow = ps[ty*8 + i];
        float4 v;
        v.x = acc[i][0] + bp[n0+tx*4+0];
        v.y = acc[i][1] + bp[n0+tx*4+1];
        v.z = acc[i][2] + bp[n0+tx*4+2];
        v.w = acc[i][3] + bp[n0+tx*4+3];
        *(float4*)(out + (size_t)prow*256 + n0 + tx*4) = v;
    }
}

// ============================================================================
extern "C" void kernel_launch(void* const* d_in, const int* in_sizes, int n_in,
                              void* d_out, int out_size, void* d_ws, size_t ws_size,
                              hipStream_t stream) {
    const float* feats   = (const float*)d_in[0];
    const float* ncoords = (const float*)d_in[1];
    const int*   perm    = (const int*)d_in[2];
    const float* qtx     = (const float*)d_in[3];
    const float* ktx     = (const float*)d_in[4];
    const float* vtx     = (const float*)d_in[5];
    const float* qtr     = (const float*)d_in[6];
    const float* ktr     = (const float*)d_in[7];
    const float* vtr     = (const float*)d_in[8];
    const float* qkv_w   = (const float*)d_in[9];
    const float* qkv_b   = (const float*)d_in[10];
    const float* proj_w  = (const float*)d_in[11];
    const float* proj_b  = (const float*)d_in[12];

    uint16_t* qkv_s  = (uint16_t*)d_ws;                                  // N*768 bf16
    uint16_t* attn_o = (uint16_t*)((char*)d_ws + (size_t)N_PTS*768*2);   // N*256 bf16

    dim3 g1(512, 12);
    qkv_gemm<<<g1, 256, 0, stream>>>(feats, perm, qkv_w, qkv_b, qkv_s);

    win_attn2<<<W_WIN, 256, 0, stream>>>(qkv_s, perm, ncoords,
                                         qtx, ktx, vtx, qtr, ktr, vtr, attn_o);

    dim3 g3(512, 4);
    proj_gemm<<<g3, 256, 0, stream>>>(attn_o, perm, proj_w, proj_b, (float*)d_out);
}

// Round 4
// 1888.128 us; speedup vs baseline: 1.6201x; 1.3070x over previous
//
#include <hip/hip_runtime.h>
#include <stdint.h>

#define N_PTS 65536
#define W_WIN 2048

using short8 = __attribute__((ext_vector_type(8))) short;
using f32x4  = __attribute__((ext_vector_type(4))) float;

// ---- bf16 helpers (RNE) ----
__device__ __forceinline__ uint16_t f2b(float x) {
    uint32_t u = __float_as_uint(x);
    u += 0x7FFFu + ((u >> 16) & 1u);
    return (uint16_t)(u >> 16);
}
__device__ __forceinline__ float b2f(uint32_t b) {
    return __uint_as_float(b << 16);
}
__device__ __forceinline__ short8 pack8(float4 a, float4 b) {
    short8 r;
    r[0]=(short)f2b(a.x); r[1]=(short)f2b(a.y); r[2]=(short)f2b(a.z); r[3]=(short)f2b(a.w);
    r[4]=(short)f2b(b.x); r[5]=(short)f2b(b.y); r[6]=(short)f2b(b.z); r[7]=(short)f2b(b.w);
    return r;
}

// ============================================================================
// Kernel 0: one-time (per launch) bf16 conversion of tables + weights.
// qt/kt: flat [lc][h][hd] (lc = concat 0..215).  vt: transposed [h][hd][232].
// ============================================================================
__global__ __launch_bounds__(256) void setup_tabs(
    const float* __restrict__ qtx, const float* __restrict__ qtr,
    const float* __restrict__ ktx, const float* __restrict__ ktr,
    const float* __restrict__ vtx, const float* __restrict__ vtr,
    const float* __restrict__ qkv_w, const float* __restrict__ proj_w,
    uint16_t* __restrict__ qt_bf, uint16_t* __restrict__ kt_bf,
    uint16_t* __restrict__ vt_bf, uint16_t* __restrict__ wq_bf,
    uint16_t* __restrict__ wp_bf)
{
    int e = blockIdx.x * 256 + threadIdx.x;
    if (e < 55296) {
        qt_bf[e] = f2b(e < 30720 ? qtx[e] : qtr[e - 30720]);
    } else if (e < 110592) {
        int u = e - 55296;
        kt_bf[u] = f2b(u < 30720 ? ktx[u] : ktr[u - 30720]);
    } else if (e < 165888) {
        int u = e - 110592;
        float v = u < 30720 ? vtx[u] : vtr[u - 30720];
        int lc = u >> 8, h = (u >> 4) & 15, c = u & 15;
        vt_bf[(h * 16 + c) * 232 + lc] = f2b(v);
    } else if (e < 362496) {
        int u = e - 165888;
        wq_bf[u] = f2b(qkv_w[u]);
    } else if (e < 428032) {
        int u = e - 362496;
        wp_bf[u] = f2b(proj_w[u]);
    }
}

// ============================================================================
// Kernel 1: qkv = feats[perm[s]] @ qkv_w^T + b  (MFMA 16x16x32 bf16)
// BM=128 BN=128, 4 waves in 2x2, each wave 64x64 (4x4 tiles), store bf16.
// ============================================================================
__global__ __launch_bounds__(256, 3) void qkv_gemm2(
    const float* __restrict__ feats, const int* __restrict__ perm,
    const uint16_t* __restrict__ wq_bf, const float* __restrict__ bq,
    uint16_t* __restrict__ qkv_out)
{
    __shared__ uint16_t Abuf[128 * 40];
    __shared__ int ps[128];
    const int t  = threadIdx.x;
    const int s0 = blockIdx.x * 128;
    const int n0 = blockIdx.y * 128;
    if (t < 128) ps[t] = perm[s0 + t];
    const int wv = t >> 6, ln = t & 63, g = ln >> 4, lr = ln & 15;
    const int wr = wv >> 1, wc = wv & 1;
    f32x4 acc[4][4];
    #pragma unroll
    for (int a = 0; a < 4; a++)
        #pragma unroll
        for (int b = 0; b < 4; b++) acc[a][b] = (f32x4){0.f,0.f,0.f,0.f};
    __syncthreads();
    for (int k0 = 0; k0 < 256; k0 += 32) {
        #pragma unroll
        for (int it = 0; it < 2; it++) {
            int idx = t + it * 256;
            int row = idx >> 2, seg = idx & 3;
            const float* p = feats + (size_t)ps[row] * 256 + k0 + seg * 8;
            *(short8*)&Abuf[row * 40 + seg * 8] = pack8(*(const float4*)p, *(const float4*)(p + 4));
        }
        __syncthreads();
        short8 bfrag[4], afrag[4];
        #pragma unroll
        for (int nt = 0; nt < 4; nt++)
            bfrag[nt] = *(const short8*)(wq_bf + (size_t)(n0 + wc*64 + nt*16 + lr) * 256 + k0 + g*8);
        #pragma unroll
        for (int mt = 0; mt < 4; mt++)
            afrag[mt] = *(const short8*)&Abuf[(wr*64 + mt*16 + lr) * 40 + g*8];
        #pragma unroll
        for (int mt = 0; mt < 4; mt++)
            #pragma unroll
            for (int nt = 0; nt < 4; nt++)
                acc[mt][nt] = __builtin_amdgcn_mfma_f32_16x16x32_bf16(afrag[mt], bfrag[nt], acc[mt][nt], 0, 0, 0);
        __syncthreads();
    }
    #pragma unroll
    for (int nt = 0; nt < 4; nt++) {
        int n = n0 + wc*64 + nt*16 + lr;
        float bias = bq[n];
        float scl = (n < 256) ? 0.25f : 1.0f;
        #pragma unroll
        for (int mt = 0; mt < 4; mt++) {
            int srow = s0 + wr*64 + mt*16 + g*4;
            #pragma unroll
            for (int r = 0; r < 4; r++)
                qkv_out[(size_t)(srow + r) * 768 + n] = f2b((acc[mt][nt][r] + bias) * scl);
        }
    }
}

// ============================================================================
// Kernel 2: per-window attention, MFMA + restructured phases (4 barriers/head)
// ============================================================================
__global__ __launch_bounds__(256, 3) void win_attn3(
    const uint16_t* __restrict__ qkv,      // [N][768] bf16, q pre-scaled
    const int* __restrict__ perm,
    const float* __restrict__ ncoords,
    const uint16_t* __restrict__ qt_bf, const uint16_t* __restrict__ kt_bf,
    const uint16_t* __restrict__ vt_bf,
    uint16_t* __restrict__ attn_o)         // [N][256] bf16
{
    __shared__ __align__(16) unsigned char smem[46720];
    uint16_t* Pqk  = (uint16_t*)(smem + 0);        // [32][264] bf16 (16896)
    uint16_t* Pkq  = (uint16_t*)(smem + 16896);    // [32][232] bf16 (14848)
    float*    Sf   = (float*)(smem + 0);           // [32][228] f32 (29184) aliases P
    float*    att  = (float*)(smem + 31744);       // [32][36] f32 (4608)
    uint16_t* vwT  = (uint16_t*)(smem + 36352);    // [16][40] bf16 (1280)
    uint8_t*  lcix = (uint8_t*)(smem + 37632);     // [6][1024] (6144)
    float*    oacc = (float*)(smem + 43776);       // [32][17] f32 (2176)
    float*    cs   = (float*)(smem + 45952);       // 192 f32 (768)

    const int t     = threadIdx.x;
    const int sBase = blockIdx.x * 32;
    const int wv = t >> 6;
    const int ln = t & 63;
    const int g  = ln >> 4;      // k-group 0..3 (g>=2 zero-padded in P phase)
    const int lr = ln & 15;

    // ---- phase 0: coords + relative concat indices (layout [m][i*32+j]) ----
    if (t < 192) {
        int i = t / 6, d = t % 6;
        int p = perm[sBase + i];
        cs[t] = ncoords[(size_t)p * 6 + d] * (d < 3 ? 4.0f : 8.0f);
    }
    __syncthreads();
    #pragma unroll
    for (int r = 0; r < 4; r++) {
        int pr = t * 4 + r;
        int i = pr >> 5, j = pr & 31;
        #pragma unroll
        for (int m = 0; m < 3; m++) {
            int ix = (int)floorf(cs[i*6+m] - cs[j*6+m]) + 20;
            ix = ix < 0 ? 0 : (ix > 39 ? 39 : ix);
            lcix[m*1024 + pr] = (uint8_t)(ix + m*40);
        }
        #pragma unroll
        for (int m = 0; m < 3; m++) {
            int ix = (int)floorf(cs[i*6+3+m] - cs[j*6+3+m]) + 16;
            ix = ix < 0 ? 0 : (ix > 31 ? 31 : ix);
            lcix[(3+m)*1024 + pr] = (uint8_t)(ix + 120 + m*32);
        }
    }
    // lcix visibility covered by b1

    const int isPkq = wv >> 1;   // waves 0,1: Pqk_ext; 2,3: Pkq
    const int mt    = wv & 1;

    for (int h = 0; h < 16; h++) {
        const int hc0 = h * 16;
        // ---------------- Phase P: vw staging + MFMA P-tables ----------------
        {   // v^T (16c x 32j)
            int e = t * 2, c = e & 15, j = e >> 4;
            uint32_t pk = *(const uint32_t*)(const void*)(qkv + (size_t)(sBase + j) * 768 + 512 + hc0 + c);
            vwT[c * 40 + j]       = (uint16_t)(pk & 0xffffu);
            vwT[(c + 1) * 40 + j] = (uint16_t)(pk >> 16);
        }
        {
            short8 afrag = {0,0,0,0,0,0,0,0};
            if (g < 2)
                afrag = *(const short8*)(const void*)(qkv + (size_t)(sBase + mt*16 + lr) * 768 + isPkq*256 + hc0 + g*8);
            const uint16_t* tabb = isPkq ? qt_bf : kt_bf;
            uint16_t* Pout = isPkq ? Pkq : Pqk;
            const int str  = isPkq ? 232 : 264;
            const int ntmax = isPkq ? 14 : 16;
            for (int nt = 0; nt < ntmax; nt++) {
                int col = nt * 16 + lr;
                short8 bfrag = {0,0,0,0,0,0,0,0};
                if (g < 2) {
                    if (col < 216)
                        bfrag = *(const short8*)(const void*)(tabb + (size_t)col * 256 + hc0 + g*8);
                    else if (!isPkq && col < 248)
                        bfrag = *(const short8*)(const void*)(qkv + (size_t)(sBase + col - 216) * 768 + 256 + hc0 + g*8);
                }
                f32x4 d = {0.f,0.f,0.f,0.f};
                d = __builtin_amdgcn_mfma_f32_16x16x32_bf16(afrag, bfrag, d, 0, 0, 0);
                #pragma unroll
                for (int r = 0; r < 4; r++)
                    Pout[(size_t)(mt*16 + g*4 + r) * str + col] = f2b(d[r]);
            }
        }
        __syncthreads();   // b1: P/vwT -> GSM

        // ---------------- Phase GSM: gather logits + softmax (fused, in regs) ----------------
        {
            int i = t >> 3, jsub = t & 7;
            const int ib = i * 264;
            float v[4]; float mx = -3.0e38f;
            #pragma unroll
            for (int jj = 0; jj < 4; jj++) {
                int j = jsub + jj * 8;
                float a = b2f(Pqk[ib + 216 + j]);
                #pragma unroll
                for (int m = 0; m < 6; m++) {
                    int lc = lcix[m*1024 + i*32 + j];
                    a += b2f(Pqk[ib + lc]) + b2f(Pkq[j * 232 + lc]);
                }
                v[jj] = a; mx = fmaxf(mx, a);
            }
            #pragma unroll
            for (int d2 = 1; d2 < 8; d2 <<= 1) mx = fmaxf(mx, __shfl_xor(mx, d2, 64));
            float sm = 0.f;
            #pragma unroll
            for (int jj = 0; jj < 4; jj++) { v[jj] = __expf(v[jj] - mx); sm += v[jj]; }
            #pragma unroll
            for (int d2 = 1; d2 < 8; d2 <<= 1) sm += __shfl_xor(sm, d2, 64);
            float inv = 1.0f / sm;
            #pragma unroll
            for (int jj = 0; jj < 4; jj++) att[i*36 + jsub + jj*8] = v[jj] * inv;
        }
        __syncthreads();   // b2: GSM P-reads done -> S-zero may overwrite; att -> ZSC

        // ---------------- Phase ZSC: zero-own-segment + scatter (no inner barrier) ----------------
        if (t < 192) {
            int i = t & 31, m = t >> 5;
            const int ss = (m < 3) ? m * 40 : 120 + (m - 3) * 32;
            const int nv = (m < 3) ? 10 : 8;
            float* Srow = &Sf[i * 228];
            float4* z = (float4*)&Srow[ss];
            for (int q = 0; q < nv; q++) z[q] = make_float4(0.f,0.f,0.f,0.f);
            float4 av[8];
            #pragma unroll
            for (int q = 0; q < 8; q++) av[q] = *(const float4*)&att[i*36 + q*4];
            const float* arow = (const float*)av;
            const uint32_t* lx = (const uint32_t*)&lcix[m*1024 + i*32];
            #pragma unroll
            for (int q = 0; q < 8; q++) {
                uint32_t pk = lx[q];
                atomicAdd(&Srow[pk & 255u],         arow[q*4+0]);
                atomicAdd(&Srow[(pk >> 8) & 255u],  arow[q*4+1]);
                atomicAdd(&Srow[(pk >> 16) & 255u], arow[q*4+2]);
                atomicAdd(&Srow[pk >> 24],          arow[q*4+3]);
            }
        } else {
            int u = t - 192;
            for (int q = u; q < 136; q += 64) ((float4*)oacc)[q] = make_float4(0.f,0.f,0.f,0.f);
            for (int q = u; q < 96; q += 64) {
                int i = q / 3, p = q % 3;
                *(float4*)&Sf[i*228 + 216 + p*4] = make_float4(0.f,0.f,0.f,0.f);
            }
        }
        __syncthreads();   // b3: S/oacc -> PV

        // ---------------- Phase PV: [S|a](32x256) @ [vtab;vw](256x16), K-split ----------------
        {
            f32x4 acc0 = {0.f,0.f,0.f,0.f}, acc1 = {0.f,0.f,0.f,0.f};
            const uint16_t* vrow = vt_bf + ((size_t)hc0 + lr) * 232;
            #pragma unroll
            for (int s2 = 0; s2 < 2; s2++) {
                int kt = wv * 2 + s2;
                short8 bfrag;
                if (kt < 7) bfrag = *(const short8*)(const void*)(vrow + kt*32 + g*8);
                else        bfrag = *(const short8*)(const void*)(vwT + lr*40 + g*8);
                {   // rows 0..15
                    short8 af;
                    if (kt < 7) {
                        const float* p = &Sf[(size_t)lr * 228 + kt*32 + g*8];
                        af = pack8(*(const float4*)p, *(const float4*)(p+4));
                    } else {
                        const float* p = &att[lr * 36 + g*8];
                        af = pack8(*(const float4*)p, *(const float4*)(p+4));
                    }
                    acc0 = __builtin_amdgcn_mfma_f32_16x16x32_bf16(af, bfrag, acc0, 0, 0, 0);
                }
                {   // rows 16..31
                    short8 af;
                    if (kt < 7) {
                        const float* p = &Sf[(size_t)(16 + lr) * 228 + kt*32 + g*8];
                        af = pack8(*(const float4*)p, *(const float4*)(p+4));
                    } else {
                        const float* p = &att[(16 + lr) * 36 + g*8];
                        af = pack8(*(const float4*)p, *(const float4*)(p+4));
                    }
                    acc1 = __builtin_amdgcn_mfma_f32_16x16x32_bf16(af, bfrag, acc1, 0, 0, 0);
                }
            }
            #pragma unroll
            for (int r = 0; r < 4; r++) {
                atomicAdd(&oacc[(g*4 + r) * 17 + lr], acc0[r]);
                atomicAdd(&oacc[(16 + g*4 + r) * 17 + lr], acc1[r]);
            }
        }
        __syncthreads();   // b4: oacc -> R

        // ---------------- Phase R: store head output ----------------
        {
            int o2 = t * 2;
            int i = o2 >> 4, c = o2 & 15;
            float x = oacc[i * 17 + c], y = oacc[i * 17 + c + 1];
            uint32_t pk = (uint32_t)f2b(x) | ((uint32_t)f2b(y) << 16);
            *(uint32_t*)(void*)(attn_o + (size_t)(sBase + i) * 256 + hc0 + c) = pk;
        }
        // next-head P writes (P-region/vwT) are safe: all threads passed b4;
        // oacc re-zero happens after next b2 (all threads past R by then).
    }
}

// ============================================================================
// Kernel 3: out[perm[s]] = attn_out[s] @ proj_w^T + proj_b  (MFMA, f32 out)
// ============================================================================
__global__ __launch_bounds__(256, 3) void proj_gemm2(
    const uint16_t* __restrict__ Abf, const int* __restrict__ perm,
    const uint16_t* __restrict__ wp_bf, const float* __restrict__ bp,
    float* __restrict__ out)
{
    __shared__ uint16_t Abuf[128 * 40];
    __shared__ int ps[128];
    const int t  = threadIdx.x;
    const int s0 = blockIdx.x * 128;
    const int n0 = blockIdx.y * 128;
    if (t < 128) ps[t] = perm[s0 + t];
    const int wv = t >> 6, ln = t & 63, g = ln >> 4, lr = ln & 15;
    const int wr = wv >> 1, wc = wv & 1;
    f32x4 acc[4][4];
    #pragma unroll
    for (int a = 0; a < 4; a++)
        #pragma unroll
        for (int b = 0; b < 4; b++) acc[a][b] = (f32x4){0.f,0.f,0.f,0.f};
    __syncthreads();
    for (int k0 = 0; k0 < 256; k0 += 32) {
        #pragma unroll
        for (int it = 0; it < 2; it++) {
            int idx = t + it * 256;
            int row = idx >> 2, seg = idx & 3;
            *(short8*)&Abuf[row * 40 + seg * 8] =
                *(const short8*)(const void*)(Abf + (size_t)(s0 + row) * 256 + k0 + seg * 8);
        }
        __syncthreads();
        short8 bfrag[4], afrag[4];
        #pragma unroll
        for (int nt = 0; nt < 4; nt++)
            bfrag[nt] = *(const short8*)(wp_bf + (size_t)(n0 + wc*64 + nt*16 + lr) * 256 + k0 + g*8);
        #pragma unroll
        for (int mt = 0; mt < 4; mt++)
            afrag[mt] = *(const short8*)&Abuf[(wr*64 + mt*16 + lr) * 40 + g*8];
        #pragma unroll
        for (int mt = 0; mt < 4; mt++)
            #pragma unroll
            for (int nt = 0; nt < 4; nt++)
                acc[mt][nt] = __builtin_amdgcn_mfma_f32_16x16x32_bf16(afrag[mt], bfrag[nt], acc[mt][nt], 0, 0, 0);
        __syncthreads();
    }
    #pragma unroll
    for (int nt = 0; nt < 4; nt++) {
        int n = n0 + wc*64 + nt*16 + lr;
        float bias = bp[n];
        #pragma unroll
        for (int mt = 0; mt < 4; mt++) {
            #pragma unroll
            for (int r = 0; r < 4; r++) {
                int prow = ps[wr*64 + mt*16 + g*4 + r];
                out[(size_t)prow * 256 + n] = acc[mt][nt][r] + bias;
            }
        }
    }
}

// ============================================================================
extern "C" void kernel_launch(void* const* d_in, const int* in_sizes, int n_in,
                              void* d_out, int out_size, void* d_ws, size_t ws_size,
                              hipStream_t stream) {
    const float* feats   = (const float*)d_in[0];
    const float* ncoords = (const float*)d_in[1];
    const int*   perm    = (const int*)d_in[2];
    const float* qtx     = (const float*)d_in[3];
    const float* ktx     = (const float*)d_in[4];
    const float* vtx     = (const float*)d_in[5];
    const float* qtr     = (const float*)d_in[6];
    const float* ktr     = (const float*)d_in[7];
    const float* vtr     = (const float*)d_in[8];
    const float* qkv_w   = (const float*)d_in[9];
    const float* qkv_b   = (const float*)d_in[10];
    const float* proj_w  = (const float*)d_in[11];
    const float* proj_b  = (const float*)d_in[12];

    char* ws = (char*)d_ws;
    uint16_t* qkv_s  = (uint16_t*)ws;                          // 100,663,296 B
    uint16_t* attn_o = (uint16_t*)(ws + 100663296);            //  33,554,432 B
    uint16_t* qt_bf  = (uint16_t*)(ws + 134217728);            //     110,592 B
    uint16_t* kt_bf  = (uint16_t*)(ws + 134328320);            //     110,592 B
    uint16_t* vt_bf  = (uint16_t*)(ws + 134438912);            //     118,784 B
    uint16_t* wq_bf  = (uint16_t*)(ws + 134557696);            //     393,216 B
    uint16_t* wp_bf  = (uint16_t*)(ws + 134950912);            //     131,072 B

    setup_tabs<<<1673, 256, 0, stream>>>(qtx, qtr, ktx, ktr, vtx, vtr,
                                         qkv_w, proj_w,
                                         qt_bf, kt_bf, vt_bf, wq_bf, wp_bf);

    dim3 g1(512, 6);
    qkv_gemm2<<<g1, 256, 0, stream>>>(feats, perm, wq_bf, qkv_b, qkv_s);

    win_attn3<<<W_WIN, 256, 0, stream>>>(qkv_s, perm, ncoords,
                                         qt_bf, kt_bf, vt_bf, attn_o);

    dim3 g3(512, 2);
    proj_gemm2<<<g3, 256, 0, stream>>>(attn_o, perm, wp_bf, proj_b, (float*)d_out);
}